// Round 8
// baseline (84.133 us; speedup 1.0000x reference)
//
#include <hip/hip_runtime.h>

#define S_TOTAL 8192
#define D_DIM   128
#define QBLK    256            // 4 waves x 64 q-rows (2 subtiles of 32)
#define NQT     32             // q-tiles of 256 rows
#define NSPL    16
#define UNITS   512            // NQT * NSPL
#define TILEB   16384          // one bf16 K or V tile in bytes (64*128*2)
#define QSCALE  0.12751879523178264f   // (1/sqrt(128)) * log2(e)
#define NEG_BIG -1.0e30f
#define THR     8.0f

typedef __attribute__((ext_vector_type(8)))  short    bf16x8;
typedef __attribute__((ext_vector_type(16))) float    f32x16;
typedef __attribute__((ext_vector_type(4)))  float    f32x4;
typedef __attribute__((ext_vector_type(4)))  unsigned u32x4;

static __device__ __forceinline__ unsigned short f2bf(float f) {
    unsigned int u = __builtin_bit_cast(unsigned int, f);
    u += 0x7FFFu + ((u >> 16) & 1u);   // RNE
    return (unsigned short)(u >> 16);
}
static __device__ __forceinline__ float bf2f(unsigned short u) {
    return __builtin_bit_cast(float, (unsigned int)u << 16);
}
static __device__ __forceinline__ void glds16(const void* g, void* l) {
    __builtin_amdgcn_global_load_lds(
        (const __attribute__((address_space(1))) void*)g,
        (__attribute__((address_space(3))) void*)l, 16, 0, 0);
}
static __device__ __forceinline__ unsigned pk2(float lo, float hi) {
    unsigned r;
    asm("v_cvt_pk_bf16_f32 %0, %1, %2" : "=v"(r) : "v"(lo), "v"(hi));
    return r;
}
static __device__ __forceinline__ void pl32swap(unsigned& x, unsigned& y) {
    asm("v_permlane32_swap_b32 %0, %1" : "+v"(x), "+v"(y));
}

// ---------------------------------------------------------------------------
// Fused pre-pass: K and V^T bf16 swizzled tiles (round-3-verified layouts).
//   b < 512  : K tiles. 16B chunk (r, slot) holds K[j*64+r][(slot^(r&15))*8..]
//   b >= 512 : V^T tiles. slot holds V[j*64+(slot^(d&7))*8 + i][d]
// ---------------------------------------------------------------------------
__global__ __launch_bounds__(256)
void prep_kv(const float* __restrict__ K, const float* __restrict__ V,
             unsigned short* __restrict__ Kswz, unsigned short* __restrict__ Vt)
{
    __shared__ float sv[64 * 68];
    const int b   = (int)blockIdx.x;
    const int tid = threadIdx.x;

    if (b < 512) {
        int c = b * 256 + tid;                // 131072 chunks
        int t = c >> 10;
        int r = (c >> 4) & 63;
        int slot = c & 15;
        int d0 = (slot ^ (r & 15)) << 3;
        const float* src = K + ((size_t)t * 64 + r) * D_DIM + d0;
        float4 a  = *reinterpret_cast<const float4*>(src);
        float4 bq = *reinterpret_cast<const float4*>(src + 4);
        bf16x8 o;
        o[0] = (short)f2bf(a.x);  o[1] = (short)f2bf(a.y);
        o[2] = (short)f2bf(a.z);  o[3] = (short)f2bf(a.w);
        o[4] = (short)f2bf(bq.x); o[5] = (short)f2bf(bq.y);
        o[6] = (short)f2bf(bq.z); o[7] = (short)f2bf(bq.w);
        *reinterpret_cast<bf16x8*>(&Kswz[(size_t)c * 8]) = o;
    } else {
        int bb = b - 512;                     // 256 blocks
        int t = bb >> 1;
        int h = bb & 1;
        #pragma unroll
        for (int it = 0; it < 4; ++it) {
            int f4 = it * 256 + tid;
            int r   = f4 >> 4;
            int c16 = (f4 & 15) << 2;
            float4 v = *reinterpret_cast<const float4*>(
                V + ((size_t)t * 64 + r) * D_DIM + h * 64 + c16);
            sv[r * 68 + c16 + 0] = v.x;
            sv[r * 68 + c16 + 1] = v.y;
            sv[r * 68 + c16 + 2] = v.z;
            sv[r * 68 + c16 + 3] = v.w;
        }
        __syncthreads();
        #pragma unroll
        for (int ii = 0; ii < 2; ++ii) {
            int cl = tid * 2 + ii;
            int dl = cl >> 3;
            int slot = cl & 7;
            int d = h * 64 + dl;
            int k0 = (slot ^ (d & 7)) << 3;
            bf16x8 o;
            #pragma unroll
            for (int i = 0; i < 8; ++i) o[i] = (short)f2bf(sv[(k0 + i) * 68 + dl]);
            *reinterpret_cast<bf16x8*>(&Vt[(size_t)t * 8192 + ((size_t)(d * 8 + slot)) * 8]) = o;
        }
    }
}

// ---------------------------------------------------------------------------
// Phase macros (statically-indexed registers; single basic block per kj).
// ---------------------------------------------------------------------------
#define QKT_M(SC, QF)                                                         \
  { _Pragma("unroll")                                                         \
    for (int r = 0; r < 16; ++r) SC[r] = 0.0f;                                \
    __builtin_amdgcn_s_setprio(1);                                            \
    _Pragma("unroll")                                                         \
    for (int dc = 0; dc < 8; ++dc) {                                          \
      bf16x8 kf_ = *reinterpret_cast<const bf16x8*>(                          \
          bK + (rK << 8) + ((((dc << 1) | hi) ^ (rK & 15)) << 4));            \
      SC = __builtin_amdgcn_mfma_f32_32x32x16_bf16(kf_, QF[dc], SC, 0, 0, 0); \
    }                                                                         \
    __builtin_amdgcn_s_setprio(0); }

// Softmax phase: branchless mask, tree max, defer-rescale, exp2+sum.
#define SM_M(SC, MR, LR, ACC, QSB)                                            \
  { const int qg_ = (QSB) + qc;                                               \
    _Pragma("unroll")                                                         \
    for (int r = 0; r < 16; ++r) {                                            \
      int kg_ = kbase + (r & 3) + 8 * (r >> 2) + 4 * hi;                      \
      SC[r] = (kg_ > qg_) ? -INFINITY : SC[r];                                \
    }                                                                         \
    float ma_ = fmaxf(fmaxf(SC[0],  SC[1]),  fmaxf(SC[2],  SC[3]));           \
    float mb_ = fmaxf(fmaxf(SC[4],  SC[5]),  fmaxf(SC[6],  SC[7]));           \
    float mc_ = fmaxf(fmaxf(SC[8],  SC[9]),  fmaxf(SC[10], SC[11]));          \
    float md_ = fmaxf(fmaxf(SC[12], SC[13]), fmaxf(SC[14], SC[15]));          \
    float mx_ = fmaxf(fmaxf(ma_, mb_), fmaxf(mc_, md_));                      \
    float tmax_ = fmaxf(mx_, __shfl_xor(mx_, 32));                            \
    if (__any(tmax_ > MR + THR)) {                                            \
      float mn_ = fmaxf(MR, tmax_);                                           \
      float fs_ = __builtin_amdgcn_exp2f(MR - mn_);                           \
      MR = mn_;                                                               \
      LR *= fs_;                                                              \
      _Pragma("unroll")                                                       \
      for (int dt = 0; dt < 4; ++dt)                                          \
        _Pragma("unroll")                                                     \
        for (int r = 0; r < 16; ++r) ACC[dt][r] *= fs_;                       \
    }                                                                         \
    float s0_ = 0.f, s1_ = 0.f, s2_ = 0.f, s3_ = 0.f;                         \
    _Pragma("unroll")                                                         \
    for (int r = 0; r < 16; r += 4) {                                         \
      float p0_ = __builtin_amdgcn_exp2f(SC[r + 0] - MR);                     \
      float p1_ = __builtin_amdgcn_exp2f(SC[r + 1] - MR);                     \
      float p2_ = __builtin_amdgcn_exp2f(SC[r + 2] - MR);                     \
      float p3_ = __builtin_amdgcn_exp2f(SC[r + 3] - MR);                     \
      SC[r + 0] = p0_; SC[r + 1] = p1_; SC[r + 2] = p2_; SC[r + 3] = p3_;     \
      s0_ += p0_; s1_ += p1_; s2_ += p2_; s3_ += p3_;                         \
    }                                                                         \
    float lt_ = (s0_ + s1_) + (s2_ + s3_);                                    \
    lt_ += __shfl_xor(lt_, 32);                                               \
    LR += lt_; }

// Pack P fragments + PV MFMAs.
#define PV_M(SC, ACC)                                                         \
  { _Pragma("unroll")                                                         \
    for (int cl = 0; cl < 2; ++cl) {                                          \
      const int rb_ = cl * 8;                                                 \
      const int ck_ = kj * 2 + cl;                                            \
      unsigned pa_ = pk2(SC[rb_ + 0], SC[rb_ + 1]);                           \
      unsigned pb_ = pk2(SC[rb_ + 4], SC[rb_ + 5]);                           \
      unsigned pc_ = pk2(SC[rb_ + 2], SC[rb_ + 3]);                           \
      unsigned pd_ = pk2(SC[rb_ + 6], SC[rb_ + 7]);                           \
      pl32swap(pa_, pb_);                                                     \
      pl32swap(pc_, pd_);                                                     \
      u32x4 t4_ = {pa_, pc_, pb_, pd_};                                       \
      bf16x8 pf_ = __builtin_bit_cast(bf16x8, t4_);                           \
      __builtin_amdgcn_s_setprio(1);                                          \
      _Pragma("unroll")                                                       \
      for (int dt = 0; dt < 4; ++dt) {                                        \
        int dV_ = dt * 32 + qc;                                               \
        int slot_ = ((ck_ << 1) | hi) ^ (dV_ & 7);                            \
        bf16x8 vf_ = *reinterpret_cast<const bf16x8*>(                        \
            bV + (dV_ << 7) + (slot_ << 4));                                  \
        ACC[dt] = __builtin_amdgcn_mfma_f32_32x32x16_bf16(vf_, pf_, ACC[dt], 0, 0, 0); \
      }                                                                       \
      __builtin_amdgcn_s_setprio(0);                                          \
    } }

// Epilogue per 32-row subtile: O^T -> LDS transpose -> NT bf16 partial stores.
#define EPI_SUB(ACC, ROFF, MR, LR)                                            \
  {                                                                           \
    _Pragma("unroll")                                                         \
    for (int dt = 0; dt < 4; ++dt)                                            \
      _Pragma("unroll")                                                       \
      for (int i = 0; i < 8; ++i) {                                           \
        unsigned pk_ = pk2(ACC[dt][2 * i], ACC[dt][2 * i + 1]);               \
        int d_ = dt * 32 + (i & 1) * 2 + (i >> 1) * 8 + 4 * hi;               \
        *reinterpret_cast<unsigned*>(&sOw[qc * 136 + d_]) = pk_;              \
      }                                                                       \
    _Pragma("unroll")                                                         \
    for (int it = 0; it < 8; ++it) {                                          \
      int flat_ = it * 64 + lane;                                             \
      int q_  = flat_ >> 4;                                                   \
      int s8_ = flat_ & 15;                                                   \
      bf16x8 v_ = *reinterpret_cast<const bf16x8*>(&sOw[q_ * 136 + s8_ * 8]); \
      __builtin_nontemporal_store(v_, reinterpret_cast<bf16x8*>(              \
          OB + ((size_t)(w * 64 + (ROFF) + q_)) * D_DIM + s8_ * 8));          \
    }                                                                         \
    if (hi == 0) {                                                            \
      mpart[unit * QBLK + w * 64 + (ROFF) + qc] = MR;                         \
      lpart[unit * QBLK + w * 64 + (ROFF) + qc] = LR;                         \
    }                                                                         \
  }

// ---------------------------------------------------------------------------
// Main kernel: QBLK=256, 4 waves x 64 q (2 subtiles sharing staged K/V frags),
// phase-interleaved subtiles, Q loaded fp32 in-kernel. 512 blocks.
// ---------------------------------------------------------------------------
__global__ __launch_bounds__(256, 2)
void attn16b(const float* __restrict__ Qg,
             const unsigned short* __restrict__ Kswz,
             const unsigned short* __restrict__ Vtswz,
             unsigned short* __restrict__ Opart,
             float* __restrict__ mpart, float* __restrict__ lpart)
{
    __shared__ char sbuf[2][2 * TILEB];           // 64 KB: [dbuf][ K | V ]

    const int bx = (int)blockIdx.x;
    const int p  = bx >> 4;                       // 0..31 (pair slot)
    const int s  = bx & 15;                       // split; bx%8 == s%8 (XCD)
    const int qt = (p < 16) ? (31 - p) : (p - 16);// long+short pairing
    const int unit   = qt * NSPL + s;
    const int jtiles = 4 * qt + 4;

    const int tid  = threadIdx.x;
    const int w    = tid >> 6;
    const int lane = tid & 63;
    const int qc   = lane & 31;
    const int hi   = lane >> 5;

    const int qw0 = qt * QBLK + w * 64;           // wave's first q-row

    // Q fragments loaded fp32 and converted once (scale+log2e folded in)
    bf16x8 qf0[8], qf1[8];
    #pragma unroll
    for (int dc = 0; dc < 8; ++dc) {
        const float* s0 = Qg + (size_t)(qw0 + qc) * D_DIM + dc * 16 + hi * 8;
        const float* s1 = Qg + (size_t)(qw0 + 32 + qc) * D_DIM + dc * 16 + hi * 8;
        float4 a0 = *reinterpret_cast<const float4*>(s0);
        float4 b0 = *reinterpret_cast<const float4*>(s0 + 4);
        float4 a1 = *reinterpret_cast<const float4*>(s1);
        float4 b1 = *reinterpret_cast<const float4*>(s1 + 4);
        bf16x8 v0, v1;
        v0[0] = (short)f2bf(a0.x * QSCALE); v0[1] = (short)f2bf(a0.y * QSCALE);
        v0[2] = (short)f2bf(a0.z * QSCALE); v0[3] = (short)f2bf(a0.w * QSCALE);
        v0[4] = (short)f2bf(b0.x * QSCALE); v0[5] = (short)f2bf(b0.y * QSCALE);
        v0[6] = (short)f2bf(b0.z * QSCALE); v0[7] = (short)f2bf(b0.w * QSCALE);
        v1[0] = (short)f2bf(a1.x * QSCALE); v1[1] = (short)f2bf(a1.y * QSCALE);
        v1[2] = (short)f2bf(a1.z * QSCALE); v1[3] = (short)f2bf(a1.w * QSCALE);
        v1[4] = (short)f2bf(b1.x * QSCALE); v1[5] = (short)f2bf(b1.y * QSCALE);
        v1[6] = (short)f2bf(b1.z * QSCALE); v1[7] = (short)f2bf(b1.w * QSCALE);
        qf0[dc] = v0;
        qf1[dc] = v1;
    }

    f32x16 acc0[4], acc1[4];
    #pragma unroll
    for (int dt = 0; dt < 4; ++dt)
        #pragma unroll
        for (int r = 0; r < 16; ++r) { acc0[dt][r] = 0.0f; acc1[dt][r] = 0.0f; }
    float m0r = NEG_BIG, l0r = 0.0f, m1r = NEG_BIG, l1r = 0.0f;

    auto STAGE = [&](int c, int j) {
        const char* gK = (const char*)Kswz + (size_t)j * TILEB;
        const char* gV = (const char*)Vtswz + (size_t)j * TILEB;
        char* lK = sbuf[c];
        char* lV = sbuf[c] + TILEB;
        #pragma unroll
        for (int it = 0; it < 4; ++it) {
            int goff = (it * 256 + tid) * 16;
            int loff = (it * 256 + (w << 6)) * 16;   // wave-uniform base
            glds16(gK + goff, lK + loff);
            glds16(gV + goff, lV + loff);
        }
    };

    int j = s, c = 0;
    if (j < jtiles) {
        STAGE(0, j);
        __syncthreads();
        for (; j < jtiles; j += NSPL) {
            int jn = j + NSPL;
            if (jn < jtiles) STAGE(c ^ 1, jn);

            const char* bK = sbuf[c];
            const char* bV = sbuf[c] + TILEB;

            #pragma unroll
            for (int kj = 0; kj < 2; ++kj) {
                const int kbase = j * 64 + kj * 32;
                if (kbase <= qw0 + 63) {              // wave-level causal skip
                    const int rK = kj * 32 + qc;
                    // Interleaved phases: QKT0, SM0, QKT1, PV0, SM1, PV1.
                    // sub0 runs unconditionally: if fully masked it is a
                    // provable no-op (all -inf -> p=0, no rescale, l+=0).
                    f32x16 sc0, sc1;
                    QKT_M(sc0, qf0);
                    SM_M(sc0, m0r, l0r, acc0, qw0);
                    QKT_M(sc1, qf1);
                    PV_M(sc0, acc0);
                    SM_M(sc1, m1r, l1r, acc1, qw0 + 32);
                    PV_M(sc1, acc1);
                }
            }
            __syncthreads();
            c ^= 1;
        }
    }

    // ---- epilogue: per-wave O^T -> LDS transpose -> NT stores ----
    unsigned short* OB = Opart + (size_t)unit * (QBLK * D_DIM);
    unsigned short* sOw = reinterpret_cast<unsigned short*>(&sbuf[0][0])
                          + w * (32 * 136 + 16);
    EPI_SUB(acc0, 0,  m0r, l0r);
    EPI_SUB(acc1, 32, m1r, l1r);
}

// ---------------------------------------------------------------------------
// merge: 16 splits per q-row (log2-domain m), NT partial loads.
// ---------------------------------------------------------------------------
__global__ __launch_bounds__(256)
void attn_mergeF(const unsigned short* __restrict__ Opart,
                 const float* __restrict__ mpart, const float* __restrict__ lpart,
                 float* __restrict__ Og)
{
    int tid = threadIdx.x;
    int row = blockIdx.x * 16 + (tid >> 4);
    int c8  = tid & 15;
    int qt    = row >> 8;
    int local = row & 255;
    int base  = qt * NSPL;

    float M = NEG_BIG;
    for (int s = 0; s < NSPL; ++s)
        M = fmaxf(M, mpart[(size_t)(base + s) * QBLK + local]);
    float L = 0.0f;
    for (int s = 0; s < NSPL; ++s)
        L += __builtin_amdgcn_exp2f(mpart[(size_t)(base + s) * QBLK + local] - M)
             * lpart[(size_t)(base + s) * QBLK + local];
    float invL = 1.0f / L;

    float a[8] = {0.f, 0.f, 0.f, 0.f, 0.f, 0.f, 0.f, 0.f};
    for (int s = 0; s < NSPL; ++s) {
        float e = __builtin_amdgcn_exp2f(mpart[(size_t)(base + s) * QBLK + local] - M);
        bf16x8 o = __builtin_nontemporal_load(reinterpret_cast<const bf16x8*>(
            &Opart[((size_t)(base + s) * QBLK + local) * D_DIM + c8 * 8]));
        #pragma unroll
        for (int i = 0; i < 8; ++i)
            a[i] += e * bf2f((unsigned short)o[i]);
    }
    float4 w0 = {a[0] * invL, a[1] * invL, a[2] * invL, a[3] * invL};
    float4 w1 = {a[4] * invL, a[5] * invL, a[6] * invL, a[7] * invL};
    float* dst = Og + (size_t)row * D_DIM + c8 * 8;
    *reinterpret_cast<float4*>(dst)     = w0;
    *reinterpret_cast<float4*>(dst + 4) = w1;
}

// ---------------------------------------------------------------------------
// Fallback (no workspace): self-contained 16x16 kernel, writes d_out directly.
// ---------------------------------------------------------------------------
__global__ __launch_bounds__(256, 2)
void attn_f32(const float* __restrict__ Qg, const float* __restrict__ Kg,
              const float* __restrict__ Vg, float* __restrict__ Og)
{
    __shared__ unsigned short sK [64 * 128];
    __shared__ unsigned short sVt[128 * 64];
    __shared__ unsigned short sP [4 * 16 * 72];

    const int qt   = (int)gridDim.y - 1 - (int)blockIdx.y;
    const int tid  = threadIdx.x;
    const int w    = tid >> 6;
    const int lane = tid & 63;
    const int g    = lane >> 4;
    const int lr   = lane & 15;

    const int qrow_base  = qt * 64 + w * 16 + g * 4;
    const int q_frag_row = qt * 64 + w * 16 + lr;

    bf16x8 qa[4];
    #pragma unroll
    for (int dc = 0; dc < 4; ++dc) {
        const float* src = Qg + q_frag_row * D_DIM + dc * 32 + g * 8;
        bf16x8 v;
        #pragma unroll
        for (int i = 0; i < 8; ++i) v[i] = (short)f2bf(src[i]);
        qa[dc] = v;
    }

    f32x4 acc[8];
    #pragma unroll
    for (int dj = 0; dj < 8; ++dj) acc[dj] = f32x4{0.f, 0.f, 0.f, 0.f};
    float m_run[4], l_run[4];
    #pragma unroll
    for (int r = 0; r < 4; ++r) { m_run[r] = -INFINITY; l_run[r] = 0.0f; }

    const float scale = 0.08838834764831845f;
    const int jtiles = qt + 1;
    unsigned short* sPw = sP + w * (16 * 72);
    char* sKc = reinterpret_cast<char*>(sK);
    char* sVc = reinterpret_cast<char*>(sVt);

    for (int j = 0; j < jtiles; ++j) {
        __syncthreads();
        #pragma unroll
        for (int it = 0; it < 8; ++it) {
            int flat4 = it * 256 + tid;
            int r  = flat4 >> 5;
            int d0 = (flat4 & 31) << 2;
            const float4 kv = *reinterpret_cast<const float4*>(
                Kg + (j * 64 + r) * D_DIM + d0);
            ushort4 wv;
            wv.x = f2bf(kv.x); wv.y = f2bf(kv.y); wv.z = f2bf(kv.z); wv.w = f2bf(kv.w);
            int byte = (r << 8) | (((d0 >> 3) ^ (r & 15)) << 4) | ((d0 & 7) << 1);
            *reinterpret_cast<ushort4*>(sKc + byte) = wv;
        }
        {
            int d = tid & 127;
            int khalf = tid >> 7;
            #pragma unroll
            for (int it = 0; it < 8; ++it) {
                int k0 = it * 8 + khalf * 4;
                const float* vsrc = Vg + (j * 64 + k0) * D_DIM + d;
                ushort4 wv;
                wv.x = f2bf(vsrc[0 * D_DIM]); wv.y = f2bf(vsrc[1 * D_DIM]);
                wv.z = f2bf(vsrc[2 * D_DIM]); wv.w = f2bf(vsrc[3 * D_DIM]);
                int byte = (d << 7) | (((k0 >> 3) ^ (d & 7)) << 4) | ((k0 & 7) << 1);
                *reinterpret_cast<ushort4*>(sVc + byte) = wv;
            }
        }
        __syncthreads();

        f32x4 sf[4];
        #pragma unroll
        for (int kj = 0; kj < 4; ++kj) {
            f32x4 accs = f32x4{0.f, 0.f, 0.f, 0.f};
            #pragma unroll
            for (int dc = 0; dc < 4; ++dc) {
                int rowk = kj * 16 + lr;
                int slot = (dc * 4 + g) ^ lr;
                bf16x8 b = *reinterpret_cast<bf16x8*>(sKc + ((rowk << 8) | (slot << 4)));
                accs = __builtin_amdgcn_mfma_f32_16x16x32_bf16(qa[dc], b, accs, 0, 0, 0);
            }
            sf[kj] = accs;
        }
        #pragma unroll
        for (int kj = 0; kj < 4; ++kj)
            #pragma unroll
            for (int r = 0; r < 4; ++r)
                sf[kj][r] *= scale;
        if (j == qt) {
            #pragma unroll
            for (int kj = 0; kj < 4; ++kj) {
                int kglob = j * 64 + kj * 16 + lr;
                #pragma unroll
                for (int r = 0; r < 4; ++r)
                    if (kglob > qrow_base + r) sf[kj][r] = -INFINITY;
            }
        }
        float tmax[4];
        #pragma unroll
        for (int r = 0; r < 4; ++r)
            tmax[r] = fmaxf(fmaxf(sf[0][r], sf[1][r]), fmaxf(sf[2][r], sf[3][r]));
        #pragma unroll
        for (int off = 1; off < 16; off <<= 1)
            #pragma unroll
            for (int r = 0; r < 4; ++r)
                tmax[r] = fmaxf(tmax[r], __shfl_xor(tmax[r], off));
        float fsc[4], lt[4];
        #pragma unroll
        for (int r = 0; r < 4; ++r) {
            float mn = fmaxf(m_run[r], tmax[r]);
            fsc[r] = __expf(m_run[r] - mn);
            m_run[r] = mn;
            lt[r] = 0.0f;
        }
        #pragma unroll
        for (int kj = 0; kj < 4; ++kj)
            #pragma unroll
            for (int r = 0; r < 4; ++r) {
                float p = __expf(sf[kj][r] - m_run[r]);
                sf[kj][r] = p;
                lt[r] += p;
            }
        #pragma unroll
        for (int off = 1; off < 16; off <<= 1)
            #pragma unroll
            for (int r = 0; r < 4; ++r)
                lt[r] += __shfl_xor(lt[r], off);
        #pragma unroll
        for (int r = 0; r < 4; ++r)
            l_run[r] = l_run[r] * fsc[r] + lt[r];
        #pragma unroll
        for (int dj = 0; dj < 8; ++dj)
            #pragma unroll
            for (int r = 0; r < 4; ++r)
                acc[dj][r] *= fsc[r];
        #pragma unroll
        for (int kj = 0; kj < 4; ++kj)
            #pragma unroll
            for (int r = 0; r < 4; ++r)
                sPw[(g * 4 + r) * 72 + kj * 16 + lr] = f2bf(sf[kj][r]);
        bf16x8 pa[2];
        #pragma unroll
        for (int kc = 0; kc < 2; ++kc)
            pa[kc] = *reinterpret_cast<bf16x8*>(sPw + lr * 72 + kc * 32 + g * 8);
        #pragma unroll
        for (int dj = 0; dj < 8; ++dj) {
            #pragma unroll
            for (int kc = 0; kc < 2; ++kc) {
                int d = dj * 16 + lr;
                int slot = (kc * 4 + g) ^ (lr & 7);
                bf16x8 b = *reinterpret_cast<bf16x8*>(sVc + ((d << 7) | (slot << 4)));
                acc[dj] = __builtin_amdgcn_mfma_f32_16x16x32_bf16(pa[kc], b, acc[dj], 0, 0, 0);
            }
        }
    }
    #pragma unroll
    for (int r = 0; r < 4; ++r) {
        float inv = 1.0f / l_run[r];
        int row = qrow_base + r;
        #pragma unroll
        for (int dj = 0; dj < 8; ++dj)
            Og[row * D_DIM + dj * 16 + lr] = acc[dj][r] * inv;
    }
}

// ---------------------------------------------------------------------------
extern "C" void kernel_launch(void* const* d_in, const int* in_sizes, int n_in,
                              void* d_out, int out_size, void* d_ws, size_t ws_size,
                              hipStream_t stream)
{
    const float* Qg = (const float*)d_in[0];
    const float* Kg = (const float*)d_in[1];
    const float* Vg = (const float*)d_in[2];
    float* Og = (float*)d_out;

    const size_t bfElems = (size_t)S_TOTAL * D_DIM;
    const size_t need = 2 * bfElems * 2                                   // Kswz,Vt
                      + (size_t)UNITS * ((size_t)QBLK * D_DIM * 2         // Opart
                                         + (size_t)QBLK * 8);             // m,l

    if (d_ws == nullptr || ws_size < need) {
        hipLaunchKernelGGL(attn_f32, dim3(1, 128), dim3(256), 0, stream,
                           Qg, Kg, Vg, Og);
        return;
    }

    unsigned short* Kswz  = (unsigned short*)d_ws;
    unsigned short* Vt    = Kswz + bfElems;
    unsigned short* Opart = Vt + bfElems;
    float* mpart = (float*)(Opart + (size_t)UNITS * QBLK * D_DIM);
    float* lpart = mpart + (size_t)UNITS * QBLK;

    hipLaunchKernelGGL(prep_kv, dim3(768), dim3(256), 0, stream,
                       Kg, Vg, Kswz, Vt);
    hipLaunchKernelGGL(attn16b, dim3(UNITS), dim3(256), 0, stream,
                       Qg, Kswz, Vt, Opart, mpart, lpart);
    hipLaunchKernelGGL(attn_mergeF, dim3(S_TOTAL / 16), dim3(256), 0, stream,
                       Opart, mpart, lpart, Og);
}

// Round 9
// 65.353 us; speedup vs baseline: 1.2874x; 1.2874x over previous
//
#include <hip/hip_runtime.h>

#define S_TOTAL 8192
#define D_DIM   128
#define QBLK    256            // 4 waves x 64 q-rows (2 subtiles of 32)
#define NQT     32             // q-tiles of 256 rows
#define NSPL    16
#define UNITS   512            // NQT * NSPL
#define TILEB   16384          // one bf16 K or V tile in bytes (64*128*2)
#define QSCALE  0.12751879523178264f   // (1/sqrt(128)) * log2(e)
#define NEG_BIG -1.0e30f
#define THR     8.0f

typedef __attribute__((ext_vector_type(8)))  short    bf16x8;
typedef __attribute__((ext_vector_type(16))) float    f32x16;
typedef __attribute__((ext_vector_type(4)))  float    f32x4;
typedef __attribute__((ext_vector_type(4)))  unsigned u32x4;

static __device__ __forceinline__ unsigned short f2bf(float f) {
    unsigned int u = __builtin_bit_cast(unsigned int, f);
    u += 0x7FFFu + ((u >> 16) & 1u);   // RNE
    return (unsigned short)(u >> 16);
}
static __device__ __forceinline__ float bf2f(unsigned short u) {
    return __builtin_bit_cast(float, (unsigned int)u << 16);
}
static __device__ __forceinline__ void glds16(const void* g, void* l) {
    __builtin_amdgcn_global_load_lds(
        (const __attribute__((address_space(1))) void*)g,
        (__attribute__((address_space(3))) void*)l, 16, 0, 0);
}
static __device__ __forceinline__ unsigned pk2(float lo, float hi) {
    unsigned r;
    asm("v_cvt_pk_bf16_f32 %0, %1, %2" : "=v"(r) : "v"(lo), "v"(hi));
    return r;
}
static __device__ __forceinline__ void pl32swap(unsigned& x, unsigned& y) {
    asm("v_permlane32_swap_b32 %0, %1" : "+v"(x), "+v"(y));
}

// ---------------------------------------------------------------------------
// Fused pre-pass (R6-verified layouts):
//   b < 1024 : Q * QSCALE -> bf16, plain row-major
//   b < 1536 : K tiles. 16B chunk (r, slot) holds K[t*64+r][(slot^(r&15))*8..]
//   b >= 1536: V^T tiles. chunk d*8+slot holds V[t*64+(slot^(d&7))*8 + i][d]
// ---------------------------------------------------------------------------
__global__ __launch_bounds__(256)
void prep_all(const float* __restrict__ Q, const float* __restrict__ K,
              const float* __restrict__ V,
              unsigned short* __restrict__ Qbf,
              unsigned short* __restrict__ Kswz,
              unsigned short* __restrict__ Vt)
{
    __shared__ float sv[64 * 68];
    const int b   = (int)blockIdx.x;
    const int tid = threadIdx.x;

    if (b < 1024) {
        int i4 = b * 256 + tid;
        const float4 v = reinterpret_cast<const float4*>(Q)[i4];
        ushort4 o;
        o.x = f2bf(v.x * QSCALE); o.y = f2bf(v.y * QSCALE);
        o.z = f2bf(v.z * QSCALE); o.w = f2bf(v.w * QSCALE);
        reinterpret_cast<ushort4*>(Qbf)[i4] = o;
    } else if (b < 1536) {
        int c = (b - 1024) * 256 + tid;       // 131072 chunks
        int t = c >> 10;
        int r = (c >> 4) & 63;
        int slot = c & 15;
        int d0 = (slot ^ (r & 15)) << 3;
        const float* src = K + ((size_t)t * 64 + r) * D_DIM + d0;
        float4 a  = *reinterpret_cast<const float4*>(src);
        float4 bq = *reinterpret_cast<const float4*>(src + 4);
        bf16x8 o;
        o[0] = (short)f2bf(a.x);  o[1] = (short)f2bf(a.y);
        o[2] = (short)f2bf(a.z);  o[3] = (short)f2bf(a.w);
        o[4] = (short)f2bf(bq.x); o[5] = (short)f2bf(bq.y);
        o[6] = (short)f2bf(bq.z); o[7] = (short)f2bf(bq.w);
        *reinterpret_cast<bf16x8*>(&Kswz[(size_t)c * 8]) = o;
    } else {
        int bb = b - 1536;                    // 256 blocks
        int t = bb >> 1;
        int h = bb & 1;
        #pragma unroll
        for (int it = 0; it < 4; ++it) {
            int f4 = it * 256 + tid;
            int r   = f4 >> 4;
            int c16 = (f4 & 15) << 2;
            float4 v = *reinterpret_cast<const float4*>(
                V + ((size_t)t * 64 + r) * D_DIM + h * 64 + c16);
            sv[r * 68 + c16 + 0] = v.x;
            sv[r * 68 + c16 + 1] = v.y;
            sv[r * 68 + c16 + 2] = v.z;
            sv[r * 68 + c16 + 3] = v.w;
        }
        __syncthreads();
        #pragma unroll
        for (int ii = 0; ii < 2; ++ii) {
            int cl = tid * 2 + ii;
            int dl = cl >> 3;
            int slot = cl & 7;
            int d = h * 64 + dl;
            int k0 = (slot ^ (d & 7)) << 3;
            bf16x8 o;
            #pragma unroll
            for (int i = 0; i < 8; ++i) o[i] = (short)f2bf(sv[(k0 + i) * 68 + dl]);
            *reinterpret_cast<bf16x8*>(&Vt[(size_t)t * 8192 + ((size_t)(d * 8 + slot)) * 8]) = o;
        }
    }
}

// ---------------------------------------------------------------------------
// Per-32-row-subtile processing (R6-verified): QK^T, mask, softmax, PV.
// Macro so acc/qf arrays stay statically indexed registers; sequential use
// keeps only one sc live at a time (no spill at acc0+acc1=128 VGPR).
// ---------------------------------------------------------------------------
#define PROC_SUB(QF, ACC, MR, LR, QSB)                                        \
  {                                                                           \
    const int qg_ = (QSB) + qc;                                               \
    f32x16 sc;                                                                \
    _Pragma("unroll")                                                         \
    for (int r = 0; r < 16; ++r) sc[r] = 0.0f;                                \
    {                                                                         \
      const int rK_ = kj * 32 + qc;                                           \
      __builtin_amdgcn_s_setprio(1);                                          \
      _Pragma("unroll")                                                       \
      for (int dc = 0; dc < 8; ++dc) {                                        \
        int slot_ = ((dc << 1) | hi) ^ (rK_ & 15);                            \
        bf16x8 kf_ = *reinterpret_cast<const bf16x8*>(                        \
            bK + (rK_ << 8) + (slot_ << 4));                                  \
        sc = __builtin_amdgcn_mfma_f32_32x32x16_bf16(kf_, QF[dc], sc, 0, 0, 0); \
      }                                                                       \
      __builtin_amdgcn_s_setprio(0);                                          \
    }                                                                         \
    if (kbase + 31 > (QSB)) {                                                 \
      _Pragma("unroll")                                                       \
      for (int r = 0; r < 16; ++r) {                                          \
        int kg_ = kbase + (r & 3) + 8 * (r >> 2) + 4 * hi;                    \
        if (kg_ > qg_) sc[r] = -INFINITY;                                     \
      }                                                                       \
    }                                                                         \
    float ma_ = fmaxf(fmaxf(sc[0],  sc[1]),  fmaxf(sc[2],  sc[3]));           \
    float mb_ = fmaxf(fmaxf(sc[4],  sc[5]),  fmaxf(sc[6],  sc[7]));           \
    float mc_ = fmaxf(fmaxf(sc[8],  sc[9]),  fmaxf(sc[10], sc[11]));          \
    float md_ = fmaxf(fmaxf(sc[12], sc[13]), fmaxf(sc[14], sc[15]));          \
    float mx_ = fmaxf(fmaxf(ma_, mb_), fmaxf(mc_, md_));                      \
    float tmax_ = fmaxf(mx_, __shfl_xor(mx_, 32));                            \
    if (__any(tmax_ > MR + THR)) {                                            \
      float mn_ = fmaxf(MR, tmax_);                                           \
      float fs_ = __builtin_amdgcn_exp2f(MR - mn_);                           \
      MR = mn_;                                                               \
      LR *= fs_;                                                              \
      _Pragma("unroll")                                                       \
      for (int dt = 0; dt < 4; ++dt)                                          \
        _Pragma("unroll")                                                     \
        for (int r = 0; r < 16; ++r) ACC[dt][r] *= fs_;                       \
    }                                                                         \
    float s0_ = 0.f, s1_ = 0.f, s2_ = 0.f, s3_ = 0.f;                         \
    _Pragma("unroll")                                                         \
    for (int r = 0; r < 16; r += 4) {                                         \
      float p0_ = __builtin_amdgcn_exp2f(sc[r + 0] - MR);                     \
      float p1_ = __builtin_amdgcn_exp2f(sc[r + 1] - MR);                     \
      float p2_ = __builtin_amdgcn_exp2f(sc[r + 2] - MR);                     \
      float p3_ = __builtin_amdgcn_exp2f(sc[r + 3] - MR);                     \
      sc[r + 0] = p0_; sc[r + 1] = p1_; sc[r + 2] = p2_; sc[r + 3] = p3_;     \
      s0_ += p0_; s1_ += p1_; s2_ += p2_; s3_ += p3_;                         \
    }                                                                         \
    float lt_ = (s0_ + s1_) + (s2_ + s3_);                                    \
    lt_ += __shfl_xor(lt_, 32);                                               \
    LR += lt_;                                                                \
    _Pragma("unroll")                                                         \
    for (int cl = 0; cl < 2; ++cl) {                                          \
      const int rb_ = cl * 8;                                                 \
      const int ck_ = kj * 2 + cl;                                            \
      unsigned pa_ = pk2(sc[rb_ + 0], sc[rb_ + 1]);                           \
      unsigned pb_ = pk2(sc[rb_ + 4], sc[rb_ + 5]);                           \
      unsigned pc_ = pk2(sc[rb_ + 2], sc[rb_ + 3]);                           \
      unsigned pd_ = pk2(sc[rb_ + 6], sc[rb_ + 7]);                           \
      pl32swap(pa_, pb_);                                                     \
      pl32swap(pc_, pd_);                                                     \
      u32x4 t4_ = {pa_, pc_, pb_, pd_};                                       \
      bf16x8 pf_ = __builtin_bit_cast(bf16x8, t4_);                           \
      __builtin_amdgcn_s_setprio(1);                                          \
      _Pragma("unroll")                                                       \
      for (int dt = 0; dt < 4; ++dt) {                                        \
        int dV_ = dt * 32 + qc;                                               \
        int slot_ = ((ck_ << 1) | hi) ^ (dV_ & 7);                            \
        bf16x8 vf_ = *reinterpret_cast<const bf16x8*>(                        \
            bV + (dV_ << 7) + (slot_ << 4));                                  \
        ACC[dt] = __builtin_amdgcn_mfma_f32_32x32x16_bf16(vf_, pf_, ACC[dt], 0, 0, 0); \
      }                                                                       \
      __builtin_amdgcn_s_setprio(0);                                          \
    }                                                                         \
  }

// Epilogue per 32-row subtile: O^T -> LDS transpose -> NT bf16 partial stores.
#define EPI_SUB(ACC, ROFF, MR, LR)                                            \
  {                                                                           \
    _Pragma("unroll")                                                         \
    for (int dt = 0; dt < 4; ++dt)                                            \
      _Pragma("unroll")                                                       \
      for (int i = 0; i < 8; ++i) {                                           \
        unsigned pk_ = pk2(ACC[dt][2 * i], ACC[dt][2 * i + 1]);               \
        int d_ = dt * 32 + (i & 1) * 2 + (i >> 1) * 8 + 4 * hi;               \
        *reinterpret_cast<unsigned*>(&sOw[qc * 136 + d_]) = pk_;              \
      }                                                                       \
    _Pragma("unroll")                                                         \
    for (int it = 0; it < 8; ++it) {                                          \
      int flat_ = it * 64 + lane;                                             \
      int q_  = flat_ >> 4;                                                   \
      int s8_ = flat_ & 15;                                                   \
      bf16x8 v_ = *reinterpret_cast<const bf16x8*>(&sOw[q_ * 136 + s8_ * 8]); \
      __builtin_nontemporal_store(v_, reinterpret_cast<bf16x8*>(              \
          OB + ((size_t)(w * 64 + (ROFF) + q_)) * D_DIM + s8_ * 8));          \
    }                                                                         \
    if (hi == 0) {                                                            \
      mpart[unit * QBLK + w * 64 + (ROFF) + qc] = MR;                         \
      lpart[unit * QBLK + w * 64 + (ROFF) + qc] = LR;                         \
    }                                                                         \
  }

// ---------------------------------------------------------------------------
// Main kernel (exact R6 structure): QBLK=256, 4 waves x 64 q, 2 subtiles
// sharing staged K/V fragments, processed sequentially. 512 blocks.
// ---------------------------------------------------------------------------
__global__ __launch_bounds__(256, 2)
void attn16(const unsigned short* __restrict__ Qbf,
            const unsigned short* __restrict__ Kswz,
            const unsigned short* __restrict__ Vtswz,
            unsigned short* __restrict__ Opart,
            float* __restrict__ mpart, float* __restrict__ lpart)
{
    __shared__ char sbuf[2][2 * TILEB];           // 64 KB: [dbuf][ K | V ]

    const int bx = (int)blockIdx.x;
    const int p  = bx >> 4;                       // 0..31 (pair slot)
    const int s  = bx & 15;                       // split; bx%8 == s%8 (XCD)
    const int qt = (p < 16) ? (31 - p) : (p - 16);// long+short pairing
    const int unit   = qt * NSPL + s;
    const int jtiles = 4 * qt + 4;

    const int tid  = threadIdx.x;
    const int w    = tid >> 6;
    const int lane = tid & 63;
    const int qc   = lane & 31;
    const int hi   = lane >> 5;

    const int qw0 = qt * QBLK + w * 64;           // wave's first q-row

    bf16x8 qf0[8], qf1[8];
    #pragma unroll
    for (int dc = 0; dc < 8; ++dc) {
        qf0[dc] = *reinterpret_cast<const bf16x8*>(
            Qbf + (size_t)(qw0 + qc) * D_DIM + dc * 16 + hi * 8);
        qf1[dc] = *reinterpret_cast<const bf16x8*>(
            Qbf + (size_t)(qw0 + 32 + qc) * D_DIM + dc * 16 + hi * 8);
    }

    f32x16 acc0[4], acc1[4];
    #pragma unroll
    for (int dt = 0; dt < 4; ++dt)
        #pragma unroll
        for (int r = 0; r < 16; ++r) { acc0[dt][r] = 0.0f; acc1[dt][r] = 0.0f; }
    float m0r = NEG_BIG, l0r = 0.0f, m1r = NEG_BIG, l1r = 0.0f;

    auto STAGE = [&](int c, int j) {
        const char* gK = (const char*)Kswz + (size_t)j * TILEB;
        const char* gV = (const char*)Vtswz + (size_t)j * TILEB;
        char* lK = sbuf[c];
        char* lV = sbuf[c] + TILEB;
        #pragma unroll
        for (int it = 0; it < 4; ++it) {
            int goff = (it * 256 + tid) * 16;
            int loff = (it * 256 + (w << 6)) * 16;   // wave-uniform base
            glds16(gK + goff, lK + loff);
            glds16(gV + goff, lV + loff);
        }
    };

    int j = s, c = 0;
    if (j < jtiles) {
        STAGE(0, j);
        __syncthreads();
        for (; j < jtiles; j += NSPL) {
            int jn = j + NSPL;
            if (jn < jtiles) STAGE(c ^ 1, jn);

            const char* bK = sbuf[c];
            const char* bV = sbuf[c] + TILEB;

            #pragma unroll
            for (int kj = 0; kj < 2; ++kj) {
                const int kbase = j * 64 + kj * 32;
                if (kbase <= qw0 + 63) {              // wave-level causal skip
                    if (kbase <= qw0 + 31)
                        PROC_SUB(qf0, acc0, m0r, l0r, qw0);
                    PROC_SUB(qf1, acc1, m1r, l1r, qw0 + 32);
                }
            }
            __syncthreads();
            c ^= 1;
        }
    }

    // ---- epilogue: per-wave O^T -> LDS transpose -> NT stores ----
    unsigned short* OB = Opart + (size_t)unit * (QBLK * D_DIM);
    unsigned short* sOw = reinterpret_cast<unsigned short*>(&sbuf[0][0])
                          + w * (32 * 136 + 16);
    EPI_SUB(acc0, 0,  m0r, l0r);
    EPI_SUB(acc1, 32, m1r, l1r);
}

// ---------------------------------------------------------------------------
// merge: 16 splits per q-row (log2-domain m), NT partial loads.
// ---------------------------------------------------------------------------
__global__ __launch_bounds__(256)
void attn_mergeF(const unsigned short* __restrict__ Opart,
                 const float* __restrict__ mpart, const float* __restrict__ lpart,
                 float* __restrict__ Og)
{
    int tid = threadIdx.x;
    int row = blockIdx.x * 16 + (tid >> 4);
    int c8  = tid & 15;
    int qt    = row >> 8;
    int local = row & 255;
    int base  = qt * NSPL;

    float M = NEG_BIG;
    for (int s = 0; s < NSPL; ++s)
        M = fmaxf(M, mpart[(size_t)(base + s) * QBLK + local]);
    float L = 0.0f;
    for (int s = 0; s < NSPL; ++s)
        L += __builtin_amdgcn_exp2f(mpart[(size_t)(base + s) * QBLK + local] - M)
             * lpart[(size_t)(base + s) * QBLK + local];
    float invL = 1.0f / L;

    float a[8] = {0.f, 0.f, 0.f, 0.f, 0.f, 0.f, 0.f, 0.f};
    for (int s = 0; s < NSPL; ++s) {
        float e = __builtin_amdgcn_exp2f(mpart[(size_t)(base + s) * QBLK + local] - M);
        bf16x8 o = __builtin_nontemporal_load(reinterpret_cast<const bf16x8*>(
            &Opart[((size_t)(base + s) * QBLK + local) * D_DIM + c8 * 8]));
        #pragma unroll
        for (int i = 0; i < 8; ++i)
            a[i] += e * bf2f((unsigned short)o[i]);
    }
    float4 w0 = {a[0] * invL, a[1] * invL, a[2] * invL, a[3] * invL};
    float4 w1 = {a[4] * invL, a[5] * invL, a[6] * invL, a[7] * invL};
    float* dst = Og + (size_t)row * D_DIM + c8 * 8;
    *reinterpret_cast<float4*>(dst)     = w0;
    *reinterpret_cast<float4*>(dst + 4) = w1;
}

// ---------------------------------------------------------------------------
// Fallback (no workspace): self-contained 16x16 kernel, writes d_out directly.
// ---------------------------------------------------------------------------
__global__ __launch_bounds__(256, 2)
void attn_f32(const float* __restrict__ Qg, const float* __restrict__ Kg,
              const float* __restrict__ Vg, float* __restrict__ Og)
{
    __shared__ unsigned short sK [64 * 128];
    __shared__ unsigned short sVt[128 * 64];
    __shared__ unsigned short sP [4 * 16 * 72];

    const int qt   = (int)gridDim.y - 1 - (int)blockIdx.y;
    const int tid  = threadIdx.x;
    const int w    = tid >> 6;
    const int lane = tid & 63;
    const int g    = lane >> 4;
    const int lr   = lane & 15;

    const int qrow_base  = qt * 64 + w * 16 + g * 4;
    const int q_frag_row = qt * 64 + w * 16 + lr;

    bf16x8 qa[4];
    #pragma unroll
    for (int dc = 0; dc < 4; ++dc) {
        const float* src = Qg + q_frag_row * D_DIM + dc * 32 + g * 8;
        bf16x8 v;
        #pragma unroll
        for (int i = 0; i < 8; ++i) v[i] = (short)f2bf(src[i]);
        qa[dc] = v;
    }

    f32x4 acc[8];
    #pragma unroll
    for (int dj = 0; dj < 8; ++dj) acc[dj] = f32x4{0.f, 0.f, 0.f, 0.f};
    float m_run[4], l_run[4];
    #pragma unroll
    for (int r = 0; r < 4; ++r) { m_run[r] = -INFINITY; l_run[r] = 0.0f; }

    const float scale = 0.08838834764831845f;
    const int jtiles = qt + 1;
    unsigned short* sPw = sP + w * (16 * 72);
    char* sKc = reinterpret_cast<char*>(sK);
    char* sVc = reinterpret_cast<char*>(sVt);

    for (int j = 0; j < jtiles; ++j) {
        __syncthreads();
        #pragma unroll
        for (int it = 0; it < 8; ++it) {
            int flat4 = it * 256 + tid;
            int r  = flat4 >> 5;
            int d0 = (flat4 & 31) << 2;
            const float4 kv = *reinterpret_cast<const float4*>(
                Kg + (j * 64 + r) * D_DIM + d0);
            ushort4 wv;
            wv.x = f2bf(kv.x); wv.y = f2bf(kv.y); wv.z = f2bf(kv.z); wv.w = f2bf(kv.w);
            int byte = (r << 8) | (((d0 >> 3) ^ (r & 15)) << 4) | ((d0 & 7) << 1);
            *reinterpret_cast<ushort4*>(sKc + byte) = wv;
        }
        {
            int d = tid & 127;
            int khalf = tid >> 7;
            #pragma unroll
            for (int it = 0; it < 8; ++it) {
                int k0 = it * 8 + khalf * 4;
                const float* vsrc = Vg + (j * 64 + k0) * D_DIM + d;
                ushort4 wv;
                wv.x = f2bf(vsrc[0 * D_DIM]); wv.y = f2bf(vsrc[1 * D_DIM]);
                wv.z = f2bf(vsrc[2 * D_DIM]); wv.w = f2bf(vsrc[3 * D_DIM]);
                int byte = (d << 7) | (((k0 >> 3) ^ (d & 7)) << 4) | ((k0 & 7) << 1);
                *reinterpret_cast<ushort4*>(sVc + byte) = wv;
            }
        }
        __syncthreads();

        f32x4 sf[4];
        #pragma unroll
        for (int kj = 0; kj < 4; ++kj) {
            f32x4 accs = f32x4{0.f, 0.f, 0.f, 0.f};
            #pragma unroll
            for (int dc = 0; dc < 4; ++dc) {
                int rowk = kj * 16 + lr;
                int slot = (dc * 4 + g) ^ lr;
                bf16x8 b = *reinterpret_cast<bf16x8*>(sKc + ((rowk << 8) | (slot << 4)));
                accs = __builtin_amdgcn_mfma_f32_16x16x32_bf16(qa[dc], b, accs, 0, 0, 0);
            }
            sf[kj] = accs;
        }
        #pragma unroll
        for (int kj = 0; kj < 4; ++kj)
            #pragma unroll
            for (int r = 0; r < 4; ++r)
                sf[kj][r] *= scale;
        if (j == qt) {
            #pragma unroll
            for (int kj = 0; kj < 4; ++kj) {
                int kglob = j * 64 + kj * 16 + lr;
                #pragma unroll
                for (int r = 0; r < 4; ++r)
                    if (kglob > qrow_base + r) sf[kj][r] = -INFINITY;
            }
        }
        float tmax[4];
        #pragma unroll
        for (int r = 0; r < 4; ++r)
            tmax[r] = fmaxf(fmaxf(sf[0][r], sf[1][r]), fmaxf(sf[2][r], sf[3][r]));
        #pragma unroll
        for (int off = 1; off < 16; off <<= 1)
            #pragma unroll
            for (int r = 0; r < 4; ++r)
                tmax[r] = fmaxf(tmax[r], __shfl_xor(tmax[r], off));
        float fsc[4], lt[4];
        #pragma unroll
        for (int r = 0; r < 4; ++r) {
            float mn = fmaxf(m_run[r], tmax[r]);
            fsc[r] = __expf(m_run[r] - mn);
            m_run[r] = mn;
            lt[r] = 0.0f;
        }
        #pragma unroll
        for (int kj = 0; kj < 4; ++kj)
            #pragma unroll
            for (int r = 0; r < 4; ++r) {
                float p = __expf(sf[kj][r] - m_run[r]);
                sf[kj][r] = p;
                lt[r] += p;
            }
        #pragma unroll
        for (int off = 1; off < 16; off <<= 1)
            #pragma unroll
            for (int r = 0; r < 4; ++r)
                lt[r] += __shfl_xor(lt[r], off);
        #pragma unroll
        for (int r = 0; r < 4; ++r)
            l_run[r] = l_run[r] * fsc[r] + lt[r];
        #pragma unroll
        for (int dj = 0; dj < 8; ++dj)
            #pragma unroll
            for (int r = 0; r < 4; ++r)
                acc[dj][r] *= fsc[r];
        #pragma unroll
        for (int kj = 0; kj < 4; ++kj)
            #pragma unroll
            for (int r = 0; r < 4; ++r)
                sPw[(g * 4 + r) * 72 + kj * 16 + lr] = f2bf(sf[kj][r]);
        bf16x8 pa[2];
        #pragma unroll
        for (int kc = 0; kc < 2; ++kc)
            pa[kc] = *reinterpret_cast<bf16x8*>(sPw + lr * 72 + kc * 32 + g * 8);
        #pragma unroll
        for (int dj = 0; dj < 8; ++dj) {
            #pragma unroll
            for (int kc = 0; kc < 2; ++kc) {
                int d = dj * 16 + lr;
                int slot = (kc * 4 + g) ^ (lr & 7);
                bf16x8 b = *reinterpret_cast<bf16x8*>(sVc + ((d << 7) | (slot << 4)));
                acc[dj] = __builtin_amdgcn_mfma_f32_16x16x32_bf16(pa[kc], b, acc[dj], 0, 0, 0);
            }
        }
    }
    #pragma unroll
    for (int r = 0; r < 4; ++r) {
        float inv = 1.0f / l_run[r];
        int row = qrow_base + r;
        #pragma unroll
        for (int dj = 0; dj < 8; ++dj)
            Og[row * D_DIM + dj * 16 + lr] = acc[dj][r] * inv;
    }
}

// ---------------------------------------------------------------------------
extern "C" void kernel_launch(void* const* d_in, const int* in_sizes, int n_in,
                              void* d_out, int out_size, void* d_ws, size_t ws_size,
                              hipStream_t stream)
{
    const float* Qg = (const float*)d_in[0];
    const float* Kg = (const float*)d_in[1];
    const float* Vg = (const float*)d_in[2];
    float* Og = (float*)d_out;

    const size_t bfElems = (size_t)S_TOTAL * D_DIM;
    const size_t need = 3 * bfElems * 2                                   // Qbf,Kswz,Vt
                      + (size_t)UNITS * ((size_t)QBLK * D_DIM * 2         // Opart
                                         + (size_t)QBLK * 8);             // m,l

    if (d_ws == nullptr || ws_size < need) {
        hipLaunchKernelGGL(attn_f32, dim3(1, 128), dim3(256), 0, stream,
                           Qg, Kg, Vg, Og);
        return;
    }

    unsigned short* Qbf   = (unsigned short*)d_ws;
    unsigned short* Kswz  = Qbf + bfElems;
    unsigned short* Vt    = Kswz + bfElems;
    unsigned short* Opart = Vt + bfElems;
    float* mpart = (float*)(Opart + (size_t)UNITS * QBLK * D_DIM);
    float* lpart = mpart + (size_t)UNITS * QBLK;

    hipLaunchKernelGGL(prep_all, dim3(1792), dim3(256), 0, stream,
                       Qg, Kg, Vg, Qbf, Kswz, Vt);
    hipLaunchKernelGGL(attn16, dim3(UNITS), dim3(256), 0, stream,
                       Qbf, Kswz, Vt, Opart, mpart, lpart);
    hipLaunchKernelGGL(attn_mergeF, dim3(S_TOTAL / 16), dim3(256), 0, stream,
                       Opart, mpart, lpart, Og);
}